// Round 1
// baseline (12395.756 us; speedup 1.0000x reference)
//
#include <hip/hip_runtime.h>
#include <hip/hip_bf16.h>

// PhasedLSTM classifier: persistent cooperative kernel.
// 8 groups (32 samples) x 32 slices (16 units) = 256 blocks (1/CU).
// Per block: 6 waves (384 thr); waves (0,1)=R0, (2,3)=W1', (4,5)=R1 matmuls,
// weights resident in VGPRs (short8 wr[16][2] = 128 VGPRs/thread).
// One intra-group (intra-XCD) barrier per round; round r computes
// L0 step r, L1 step r-1, head step r-2 (501 barriers, 502 rounds).

#define NB 256
#define NTHR 384
#define T_STEPS 500
#define RON 0.05f
#define ALPHA_LEAK 1e-3f

typedef short short8 __attribute__((ext_vector_type(8)));
typedef float f32x4 __attribute__((ext_vector_type(4)));

// ---------------- ws layout (bytes) ----------------
#define OFF_WSWZ 0u              // 6291456  swizzled bf16 weights
#define OFF_U1   6291456u        // 8192     be0 @ W1
#define OFF_V1   6299648u        // 8192     g0  @ W1
#define OFF_WFP  6307840u        // 20480    g1 (.) Wf   (f32)
#define OFF_UFV  6328320u        // 128      uf[10] (incl bf), vf[10] at +16 floats
#define OFF_H0B  6328448u        // 524288   [2][8][16384] bf16, frag order
#define OFF_H1B  6852736u        // 524288
#define OFF_ST0  7377024u        // 131072   [2][8][32][32][2] f32
#define OFF_ST1  7508096u        // 131072
#define OFF_CNT  7639168u        // 2048     [8] counters (64-u32 stride)
#define ZERO_BYTES (524288u*2u + 131072u*2u + 2048u)
#define SMEM_BYTES 90112   // >160KB/2 -> forces 1 block/CU (74240 actually used)

__device__ __forceinline__ short f2bf(float x) {
  unsigned u = __float_as_uint(x);
  unsigned r = (u + 0x7fffu + ((u >> 16) & 1u)) >> 16;
  return (short)r;
}
__device__ __forceinline__ float bf2f(short s) {
  return __uint_as_float(((unsigned)(unsigned short)s) << 16);
}
__device__ __forceinline__ float sigm(float x) {
  return 1.f / (1.f + __expf(-x));
}
__device__ __forceinline__ float tanh_f(float x) {
  float cx = fminf(fmaxf(x, -15.f), 15.f);
  float e = __expf(2.f * cx);
  return (e - 1.f) / (e + 1.f);
}
// jnp.mod semantics (non-negative result)
__device__ __forceinline__ float timegate(float t, float tau, float s) {
  float phi = fmodf(t - s, tau);
  if (phi < 0.f) phi += tau;
  phi /= tau;
  return phi < 0.5f * RON ? (2.f / RON) * phi
       : (phi < RON ? 2.f - (2.f / RON) * phi : ALPHA_LEAK * phi);
}
// element index (in shorts) of activation value (sample m, unit/feature k)
// inside a [32][512] bf16 buffer stored in 16x16x32-MFMA A-fragment order.
__device__ __forceinline__ int fragidx(int m, int k) {
  return ((((k >> 5) * 2 + (m >> 4)) * 64) + (((k >> 3) & 3) * 16) + (m & 15)) * 8 + (k & 7);
}

// ---------------- prep kernels ----------------
// Swizzle R0, g0*W1, R1 -> bf16 B-fragment order, per (slice,matmul,colhalf) wave chunk.
__global__ void prep_weights(const float* __restrict__ R0, const float* __restrict__ W1,
                             const float* __restrict__ R1, const float* __restrict__ g0,
                             short* __restrict__ Wswz) {
  int t = blockIdx.x * 256 + threadIdx.x;   // < 393216
  int lane = t & 63; int rest = t >> 6;
  int nf = rest & 1;  rest >>= 1;
  int kb = rest & 15; rest >>= 4;
  int ch = rest & 1;  rest >>= 1;
  int mm = rest % 3;  int slice = rest / 3;   // slice < 32
  int c = ch * 32 + nf * 16 + (lane & 15);    // slice-local col, gate-major
  int gate = c >> 4;
  int unit = slice * 16 + (c & 15);
  int gcol = gate * 512 + unit;
  int k0 = kb * 32 + (lane >> 4) * 8;
  const float* src = (mm == 0) ? R0 : (mm == 1 ? W1 : R1);
  short8 o;
  #pragma unroll
  for (int e = 0; e < 8; ++e) {
    float v = src[(size_t)(k0 + e) * 2048 + gcol];
    if (mm == 1) v *= g0[k0 + e];
    o[e] = f2bf(v);
  }
  *(short8*)(Wswz + (size_t)t * 8) = o;
}

__global__ void prep_vecs(const float* __restrict__ W1, const float* __restrict__ g0,
                          const float* __restrict__ be0,
                          float* __restrict__ u1, float* __restrict__ v1) {
  int c = blockIdx.x * 256 + threadIdx.x;  // < 2048
  float su = 0.f, sv = 0.f;
  for (int k = 0; k < 512; ++k) {
    float w = W1[(size_t)k * 2048 + c];
    su += be0[k] * w; sv += g0[k] * w;
  }
  u1[c] = su; v1[c] = sv;
}

__global__ void prep_head(const float* __restrict__ Wf, const float* __restrict__ g1,
                          const float* __restrict__ be1, const float* __restrict__ bfv,
                          float* __restrict__ Wfp, float* __restrict__ ufv) {
  int t = blockIdx.x * 256 + threadIdx.x;
  if (t < 5120) {
    int k = t / 10;
    Wfp[t] = g1[k] * Wf[t];
  }
  if (t < 10) {
    float su = bfv[t], sv = 0.f;
    for (int k = 0; k < 512; ++k) {
      float w = Wf[k * 10 + t];
      su += be1[k] * w; sv += g1[k] * w;
    }
    ufv[t] = su; ufv[16 + t] = sv;
  }
}

// ---------------- persistent kernel ----------------
__launch_bounds__(NTHR, 2)
__global__ void plstm_persist(
    const float* __restrict__ x, const float* __restrict__ times,
    const float* __restrict__ W0, const float* __restrict__ b0,
    const float* __restrict__ tau0, const float* __restrict__ s0,
    const float* __restrict__ b1, const float* __restrict__ tau1, const float* __restrict__ s1,
    const short* __restrict__ Wswz, const float* __restrict__ u1v, const float* __restrict__ v1v,
    const float* __restrict__ Wfp, const float* __restrict__ ufv,
    short* __restrict__ H0b, short* __restrict__ H1b,
    float* __restrict__ St0, float* __restrict__ St1,
    unsigned* __restrict__ cnt, float* __restrict__ out) {
  extern __shared__ char smem[];
  short* h0b = (short*)smem;                 // 32KB, unioned with zbuf
  float* zbv = (float*)smem;                 // zb[mm] at mm*2112 floats ([32][66])
  short* h1b = (short*)(smem + 32768);       // 32KB
  float* h0f = (float*)(smem + 65536);       // [32][16]
  float* c0f = h0f + 512;
  float* h1f = h0f + 1024;
  float* c1f = h0f + 1536;
  float* mu0 = h0f + 2048; float* rs0 = mu0 + 32;
  float* mu1 = mu0 + 64;   float* rs1 = mu0 + 96;

  const int tid = threadIdx.x;
  const int g = blockIdx.x & 7;        // group == XCD (round-robin heuristic)
  const int slice = blockIdx.x >> 3;   // 0..31
  const int wid = tid >> 6, lane = tid & 63;
  const int mm = wid >> 1, ch = wid & 1;
  const int gm0 = g * 32;

  for (int i = tid; i < 2048; i += NTHR) h0f[i] = 0.f;  // h0f..c1f zero

  // resident weights: 16 k-blocks x 2 n-frags (16 cols each) = 128 VGPRs
  short8 wr[16][2];
  {
    const short* wb = Wswz + ((((size_t)slice * 3 + mm) * 2 + ch) * 32 * 64) * 8;
    #pragma unroll
    for (int kb = 0; kb < 16; ++kb)
      #pragma unroll
      for (int nf = 0; nf < 2; ++nf)
        wr[kb][nf] = *(const short8*)(wb + ((kb * 2 + nf) * 64 + lane) * 8);
  }
  __syncthreads();

  for (int r = 0; r < T_STEPS + 2; ++r) {
    const int bufA = (r + 1) & 1;   // (r-1)&1
    const int bufB = r & 1;
    // ---- stage: exchange buffers -> LDS, finalize LN stats ----
    {
      const short8* srcA = (const short8*)(H0b + ((size_t)bufA * 8 + g) * 16384);
      const short8* srcB = (const short8*)(H1b + ((size_t)bufB * 8 + g) * 16384);
      short8* dA = (short8*)h0b; short8* dB = (short8*)h1b;
      for (int i = tid; i < 2048; i += NTHR) { dA[i] = srcA[i]; dB[i] = srcB[i]; }
      if (tid < 32) {
        const float* st = St0 + ((size_t)bufA * 8 + g) * 2048;
        float s_ = 0.f, q_ = 0.f;
        for (int sl = 0; sl < 32; ++sl) { s_ += st[(sl * 32 + tid) * 2]; q_ += st[(sl * 32 + tid) * 2 + 1]; }
        float mu = s_ * (1.f / 512.f);
        float var = q_ * (1.f / 512.f) - mu * mu;
        mu0[tid] = mu; rs0[tid] = rsqrtf(var + 1e-3f);
      } else if (tid < 64) {
        int m = tid - 32;
        const float* st = St1 + ((size_t)bufB * 8 + g) * 2048;
        float s_ = 0.f, q_ = 0.f;
        for (int sl = 0; sl < 32; ++sl) { s_ += st[(sl * 32 + m) * 2]; q_ += st[(sl * 32 + m) * 2 + 1]; }
        float mu = s_ * (1.f / 512.f);
        float var = q_ * (1.f / 512.f) - mu * mu;
        mu1[m] = mu; rs1[m] = rsqrtf(var + 1e-3f);
      }
    }
    __syncthreads();
    // ---- MFMA: z-slice = A @ Wslice ----
    f32x4 acc[2][2] = {};
    {
      const short* asrc = (mm == 2) ? h1b : h0b;   // R1 reads h1[r-2], R0/W1' read h0[r-1]
      #pragma unroll
      for (int kb = 0; kb < 16; ++kb) {
        short8 a0 = *(const short8*)(asrc + ((kb * 2 + 0) * 64 + lane) * 8);
        short8 a1 = *(const short8*)(asrc + ((kb * 2 + 1) * 64 + lane) * 8);
        #pragma unroll
        for (int nf = 0; nf < 2; ++nf) {
          acc[0][nf] = __builtin_amdgcn_mfma_f32_16x16x32_bf16(a0, wr[kb][nf], acc[0][nf], 0, 0, 0);
          acc[1][nf] = __builtin_amdgcn_mfma_f32_16x16x32_bf16(a1, wr[kb][nf], acc[1][nf], 0, 0, 0);
        }
      }
    }
    __syncthreads();              // all waves done reading h0b before zbuf overwrites it
    {
      float* z = zbv + mm * 2112;
      #pragma unroll
      for (int mf = 0; mf < 2; ++mf)
        #pragma unroll
        for (int nf = 0; nf < 2; ++nf)
          #pragma unroll
          for (int q = 0; q < 4; ++q) {
            int row = mf * 16 + (lane >> 4) * 4 + q;
            int col = ch * 32 + nf * 16 + (lane & 15);
            z[row * 66 + col] = acc[mf][nf][q];
          }
    }
    __syncthreads();
    // ---- combine: gates, cell/phase updates ----
    const bool l0act = (r < T_STEPS);
    const bool l1act = (r >= 1 && r <= T_STEPS);
    for (int it = tid; it < 1024; it += NTHR) {
      int layer = it >> 9;
      int id = it & 511;
      int m = id >> 4, u = id & 15;
      int uglob = slice * 16 + u;
      if (layer == 0) {
        if (!l0act) continue;
        const float* xp = x + ((size_t)(gm0 + m) * T_STEPS + r) * 3;
        float x0 = xp[0], x1 = xp[1], x2 = xp[2];
        float zg4[4];
        #pragma unroll
        for (int q = 0; q < 4; ++q) {
          int gcol = q * 512 + uglob;
          zg4[q] = zbv[m * 66 + q * 16 + u] + b0[gcol]
                 + x0 * W0[gcol] + x1 * W0[2048 + gcol] + x2 * W0[4096 + gcol];
        }
        float iv = sigm(zg4[0]), fv = sigm(zg4[1]), gv = tanh_f(zg4[2]), ov = sigm(zg4[3]);
        float cold = c0f[id], hold = h0f[id];
        float cp = fv * cold + iv * gv;
        float hp = ov * tanh_f(cp);
        float k = timegate(times[(size_t)(gm0 + m) * T_STEPS + r], tau0[uglob], s0[uglob]);
        float hn = k * hp + (1.f - k) * hold;
        float cn = k * cp + (1.f - k) * cold;
        h0f[id] = hn; c0f[id] = cn;
        H0b[((size_t)bufB * 8 + g) * 16384 + fragidx(m, uglob)] = f2bf(hn);
      } else {
        if (!l1act) continue;
        float mu0m = mu0[m], rs0m = rs0[m];
        float zg4[4];
        #pragma unroll
        for (int q = 0; q < 4; ++q) {
          int c = q * 16 + u;
          int gcol = q * 512 + uglob;
          float zA = zbv[2112 + m * 66 + c];   // h0 @ (g0.W1)
          float zB = zbv[4224 + m * 66 + c];   // h1 @ R1
          zg4[q] = rs0m * zA + zB + b1[gcol] + u1v[gcol] - mu0m * rs0m * v1v[gcol];
        }
        float iv = sigm(zg4[0]), fv = sigm(zg4[1]), gv = tanh_f(zg4[2]), ov = sigm(zg4[3]);
        float cold = c1f[id], hold = h1f[id];
        float cp = fv * cold + iv * gv;
        float hp = ov * tanh_f(cp);
        float k = timegate(times[(size_t)(gm0 + m) * T_STEPS + (r - 1)], tau1[uglob], s1[uglob]);
        float hn = k * hp + (1.f - k) * hold;
        float cn = k * cp + (1.f - k) * cold;
        h1f[id] = hn; c1f[id] = cn;
        H1b[((size_t)bufA * 8 + g) * 16384 + fragidx(m, uglob)] = f2bf(hn);
      }
    }
    __syncthreads();
    // ---- partial LN stats + classifier head ----
    if (tid < 32) {
      if (l0act) {
        float s_ = 0.f, q_ = 0.f;
        #pragma unroll
        for (int u = 0; u < 16; ++u) { float v = h0f[tid * 16 + u]; s_ += v; q_ += v * v; }
        float* st = St0 + ((size_t)bufB * 8 + g) * 2048 + (slice * 32 + tid) * 2;
        st[0] = s_; st[1] = q_;
      }
    } else if (tid < 64) {
      if (l1act) {
        int m = tid - 32;
        float s_ = 0.f, q_ = 0.f;
        #pragma unroll
        for (int u = 0; u < 16; ++u) { float v = h1f[m * 16 + u]; s_ += v; q_ += v * v; }
        float* st = St1 + ((size_t)bufA * 8 + g) * 2048 + (slice * 32 + m) * 2;
        st[0] = s_; st[1] = q_;
      }
    } else if (wid == 1) {
      if (r >= 2) {  // head for step r-2, sample (g, slice); h1b holds version r-2
        int msam = slice;
        float lg[10];
        #pragma unroll
        for (int c = 0; c < 10; ++c) lg[c] = 0.f;
        for (int kk = 0; kk < 8; ++kk) {
          int k = lane * 8 + kk;
          float hv = bf2f(h1b[fragidx(msam, k)]);
          const float* wf = Wfp + k * 10;
          #pragma unroll
          for (int c = 0; c < 10; ++c) lg[c] += hv * wf[c];
        }
        #pragma unroll
        for (int off = 32; off > 0; off >>= 1)
          #pragma unroll
          for (int c = 0; c < 10; ++c) lg[c] += __shfl_down(lg[c], off, 64);
        if (lane == 0) {
          float m1 = mu1[msam], r1 = rs1[msam];
          float logit[10], mx = -1e30f;
          #pragma unroll
          for (int c = 0; c < 10; ++c) {
            logit[c] = r1 * lg[c] + ufv[c] - m1 * r1 * ufv[16 + c];
            mx = fmaxf(mx, logit[c]);
          }
          float ssum = 0.f;
          #pragma unroll
          for (int c = 0; c < 10; ++c) { logit[c] = expf(logit[c] - mx); ssum += logit[c]; }
          float inv = 1.f / ssum;
          float* op = out + ((size_t)(gm0 + msam) * T_STEPS + (r - 2)) * 10;
          #pragma unroll
          for (int c = 0; c < 10; ++c) op[c] = logit[c] * inv;
        }
      }
    }
    __syncthreads();
    // ---- intra-group barrier (group == XCD) ----
    if (r < T_STEPS + 1) {
      if (tid == 0) {
        __threadfence();
        __hip_atomic_fetch_add(&cnt[g * 64], 1u, __ATOMIC_ACQ_REL, __HIP_MEMORY_SCOPE_AGENT);
        unsigned tgt = 32u * (unsigned)(r + 1);
        while (__hip_atomic_load(&cnt[g * 64], __ATOMIC_RELAXED, __HIP_MEMORY_SCOPE_AGENT) < tgt)
          __builtin_amdgcn_s_sleep(8);
        __threadfence();
      }
      __syncthreads();
    }
  }
}

extern "C" void kernel_launch(void* const* d_in, const int* in_sizes, int n_in,
                              void* d_out, int out_size, void* d_ws, size_t ws_size,
                              hipStream_t stream) {
  const float* x    = (const float*)d_in[0];
  const float* tms  = (const float*)d_in[1];
  const float* W0   = (const float*)d_in[2];
  const float* R0   = (const float*)d_in[3];
  const float* b0   = (const float*)d_in[4];
  const float* tau0 = (const float*)d_in[5];
  const float* s0   = (const float*)d_in[6];
  const float* g0   = (const float*)d_in[7];
  const float* be0  = (const float*)d_in[8];
  const float* W1   = (const float*)d_in[9];
  const float* R1   = (const float*)d_in[10];
  const float* b1   = (const float*)d_in[11];
  const float* tau1 = (const float*)d_in[12];
  const float* s1   = (const float*)d_in[13];
  const float* g1   = (const float*)d_in[14];
  const float* be1  = (const float*)d_in[15];
  const float* Wf   = (const float*)d_in[16];
  const float* bfv  = (const float*)d_in[17];

  char* ws = (char*)d_ws;
  short* Wswz = (short*)(ws + OFF_WSWZ);
  float* u1   = (float*)(ws + OFF_U1);
  float* v1   = (float*)(ws + OFF_V1);
  float* Wfp  = (float*)(ws + OFF_WFP);
  float* ufv  = (float*)(ws + OFF_UFV);
  short* H0b  = (short*)(ws + OFF_H0B);
  short* H1b  = (short*)(ws + OFF_H1B);
  float* St0  = (float*)(ws + OFF_ST0);
  float* St1  = (float*)(ws + OFF_ST1);
  unsigned* cnt = (unsigned*)(ws + OFF_CNT);

  hipFuncSetAttribute(reinterpret_cast<const void*>(plstm_persist),
                      hipFuncAttributeMaxDynamicSharedMemorySize, SMEM_BYTES);

  prep_weights<<<1536, 256, 0, stream>>>(R0, W1, R1, g0, Wswz);
  prep_vecs<<<8, 256, 0, stream>>>(W1, g0, be0, u1, v1);
  prep_head<<<20, 256, 0, stream>>>(Wf, g1, be1, bfv, Wfp, ufv);
  hipMemsetAsync(ws + OFF_H0B, 0, ZERO_BYTES, stream);
  plstm_persist<<<NB, NTHR, SMEM_BYTES, stream>>>(
      x, tms, W0, b0, tau0, s0, b1, tau1, s1,
      Wswz, u1, v1, Wfp, ufv, H0b, H1b, St0, St1, cnt, (float*)d_out);
}

// Round 2
// 8234.453 us; speedup vs baseline: 1.5054x; 1.5054x over previous
//
#include <hip/hip_runtime.h>
#include <hip/hip_bf16.h>

// PhasedLSTM classifier: persistent cooperative kernel.
// 8 groups (32 samples) x 32 slices (16 units) = 256 blocks (1/CU).
// Cross-block exchange via RELAXED agent-scope atomics (global_* sc1 ->
// coherent at Infinity Cache, NO buffer_wbl2/buffer_inv L2 flushes).
// Round r computes L0 step r, L1 step r-1, head step r-2.

#define NB 256
#define NTHR 384
#define T_STEPS 500
#define RON 0.05f
#define ALPHA_LEAK 1e-3f

typedef short short8 __attribute__((ext_vector_type(8)));
typedef float f32x4 __attribute__((ext_vector_type(4)));

// ---------------- ws layout (bytes) ----------------
#define OFF_WSWZ 0u              // 6291456  swizzled bf16 weights
#define OFF_U1   6291456u        // 8192     be0 @ W1
#define OFF_V1   6299648u        // 8192     g0  @ W1
#define OFF_WFP  6307840u        // 20480    g1 (.) Wf   (f32)
#define OFF_UFV  6328320u        // 128      uf[10] (incl bf), vf[10] at +16 floats
#define OFF_H0B  6328448u        // 524288   [2][8][16384] bf16, frag order
#define OFF_H1B  6852736u        // 524288
#define OFF_ST0  7377024u        // 131072   [2][8][32][32][2] f32
#define OFF_ST1  7508096u        // 131072
#define OFF_CNT  7639168u        // 2048     [8] counters (64-u32 stride)
#define ZERO_BYTES (524288u*2u + 131072u*2u + 2048u)
#define SMEM_BYTES 90112   // >160KB/2 -> forces 1 block/CU (74240 actually used)

#define AT_LD(p)    __hip_atomic_load((p), __ATOMIC_RELAXED, __HIP_MEMORY_SCOPE_AGENT)
#define AT_ST(p, v) __hip_atomic_store((p), (v), __ATOMIC_RELAXED, __HIP_MEMORY_SCOPE_AGENT)

__device__ __forceinline__ short f2bf(float x) {
  unsigned u = __float_as_uint(x);
  unsigned r = (u + 0x7fffu + ((u >> 16) & 1u)) >> 16;
  return (short)r;
}
__device__ __forceinline__ float bf2f(short s) {
  return __uint_as_float(((unsigned)(unsigned short)s) << 16);
}
__device__ __forceinline__ float sigm(float x) {
  return 1.f / (1.f + __expf(-x));
}
__device__ __forceinline__ float tanh_f(float x) {
  float cx = fminf(fmaxf(x, -15.f), 15.f);
  float e = __expf(2.f * cx);
  return (e - 1.f) / (e + 1.f);
}
// jnp.mod semantics (non-negative result)
__device__ __forceinline__ float timegate(float t, float tau, float s) {
  float phi = fmodf(t - s, tau);
  if (phi < 0.f) phi += tau;
  phi /= tau;
  return phi < 0.5f * RON ? (2.f / RON) * phi
       : (phi < RON ? 2.f - (2.f / RON) * phi : ALPHA_LEAK * phi);
}
// element index (in shorts) of activation value (sample m, unit/feature k)
// inside a [32][512] bf16 buffer stored in 16x16x32-MFMA A-fragment order.
__device__ __forceinline__ int fragidx(int m, int k) {
  return ((((k >> 5) * 2 + (m >> 4)) * 64) + (((k >> 3) & 3) * 16) + (m & 15)) * 8 + (k & 7);
}

// ---------------- prep kernels ----------------
__global__ void prep_weights(const float* __restrict__ R0, const float* __restrict__ W1,
                             const float* __restrict__ R1, const float* __restrict__ g0,
                             short* __restrict__ Wswz) {
  int t = blockIdx.x * 256 + threadIdx.x;   // < 393216
  int lane = t & 63; int rest = t >> 6;
  int nf = rest & 1;  rest >>= 1;
  int kb = rest & 15; rest >>= 4;
  int ch = rest & 1;  rest >>= 1;
  int mm = rest % 3;  int slice = rest / 3;   // slice < 32
  int c = ch * 32 + nf * 16 + (lane & 15);    // slice-local col, gate-major
  int gate = c >> 4;
  int unit = slice * 16 + (c & 15);
  int gcol = gate * 512 + unit;
  int k0 = kb * 32 + (lane >> 4) * 8;
  const float* src = (mm == 0) ? R0 : (mm == 1 ? W1 : R1);
  short8 o;
  #pragma unroll
  for (int e = 0; e < 8; ++e) {
    float v = src[(size_t)(k0 + e) * 2048 + gcol];
    if (mm == 1) v *= g0[k0 + e];
    o[e] = f2bf(v);
  }
  *(short8*)(Wswz + (size_t)t * 8) = o;
}

__global__ void prep_vecs(const float* __restrict__ W1, const float* __restrict__ g0,
                          const float* __restrict__ be0,
                          float* __restrict__ u1, float* __restrict__ v1) {
  int c = blockIdx.x * 256 + threadIdx.x;  // < 2048
  float su = 0.f, sv = 0.f;
  for (int k = 0; k < 512; ++k) {
    float w = W1[(size_t)k * 2048 + c];
    su += be0[k] * w; sv += g0[k] * w;
  }
  u1[c] = su; v1[c] = sv;
}

__global__ void prep_head(const float* __restrict__ Wf, const float* __restrict__ g1,
                          const float* __restrict__ be1, const float* __restrict__ bfv,
                          float* __restrict__ Wfp, float* __restrict__ ufv) {
  int t = blockIdx.x * 256 + threadIdx.x;
  if (t < 5120) {
    int k = t / 10;
    Wfp[t] = g1[k] * Wf[t];
  }
  if (t < 10) {
    float su = bfv[t], sv = 0.f;
    for (int k = 0; k < 512; ++k) {
      float w = Wf[k * 10 + t];
      su += be1[k] * w; sv += g1[k] * w;
    }
    ufv[t] = su; ufv[16 + t] = sv;
  }
}

// ---------------- persistent kernel ----------------
__launch_bounds__(NTHR, 1)
__global__ void plstm_persist(
    const float* __restrict__ x, const float* __restrict__ times,
    const float* __restrict__ W0, const float* __restrict__ b0,
    const float* __restrict__ tau0, const float* __restrict__ s0,
    const float* __restrict__ b1, const float* __restrict__ tau1, const float* __restrict__ s1,
    const short* __restrict__ Wswz, const float* __restrict__ u1v, const float* __restrict__ v1v,
    const float* __restrict__ Wfp, const float* __restrict__ ufv,
    short* __restrict__ H0b, short* __restrict__ H1b,
    float* __restrict__ St0, float* __restrict__ St1,
    unsigned* __restrict__ cnt, float* __restrict__ out) {
  extern __shared__ char smem[];
  short* h0b = (short*)smem;                 // 32KB, unioned with zbuf
  float* zbv = (float*)smem;                 // zb[mm] at mm*2112 floats ([32][66])
  short* h1b = (short*)(smem + 32768);       // 32KB
  float* h0f = (float*)(smem + 65536);       // [32][16]
  float* c0f = h0f + 512;
  float* h1f = h0f + 1024;
  float* c1f = h0f + 1536;
  float* mu0 = h0f + 2048; float* rs0 = mu0 + 32;
  float* mu1 = mu0 + 64;   float* rs1 = mu0 + 96;

  const int tid = threadIdx.x;
  const int g = blockIdx.x & 7;        // group (XCD round-robin heuristic)
  const int slice = blockIdx.x >> 3;   // 0..31
  const int wid = tid >> 6, lane = tid & 63;
  const int mm = wid >> 1, ch = wid & 1;
  const int gm0 = g * 32;

  for (int i = tid; i < 2048; i += NTHR) h0f[i] = 0.f;  // h0f..c1f zero

  // resident weights: 16 k-blocks x 2 n-frags (16 cols each) = 128 VGPRs
  short8 wr[16][2];
  {
    const short* wb = Wswz + ((((size_t)slice * 3 + mm) * 2 + ch) * 32 * 64) * 8;
    #pragma unroll
    for (int kb = 0; kb < 16; ++kb)
      #pragma unroll
      for (int nf = 0; nf < 2; ++nf)
        wr[kb][nf] = *(const short8*)(wb + ((kb * 2 + nf) * 64 + lane) * 8);
  }
  __syncthreads();

  for (int r = 0; r < T_STEPS + 2; ++r) {
    const int bufA = (r + 1) & 1;   // (r-1)&1
    const int bufB = r & 1;
    // ---- stage: exchange buffers -> LDS (sc1 loads), finalize LN stats ----
    {
      const unsigned long long* srcA =
          (const unsigned long long*)(H0b + ((size_t)bufA * 8 + g) * 16384);
      const unsigned long long* srcB =
          (const unsigned long long*)(H1b + ((size_t)bufB * 8 + g) * 16384);
      unsigned long long* dA = (unsigned long long*)h0b;
      unsigned long long* dB = (unsigned long long*)h1b;
      for (int i = tid; i < 4096; i += NTHR) {
        dA[i] = AT_LD(&srcA[i]);
        dB[i] = AT_LD(&srcB[i]);
      }
      if (tid < 32) {
        const float* st = St0 + ((size_t)bufA * 8 + g) * 2048;
        float s_ = 0.f, q_ = 0.f;
        #pragma unroll
        for (int sl = 0; sl < 32; ++sl) {
          unsigned long long v = AT_LD((const unsigned long long*)(st + (sl * 32 + tid) * 2));
          s_ += __uint_as_float((unsigned)v);
          q_ += __uint_as_float((unsigned)(v >> 32));
        }
        float mu = s_ * (1.f / 512.f);
        float var = q_ * (1.f / 512.f) - mu * mu;
        mu0[tid] = mu; rs0[tid] = rsqrtf(var + 1e-3f);
      } else if (tid < 64) {
        int m = tid - 32;
        const float* st = St1 + ((size_t)bufB * 8 + g) * 2048;
        float s_ = 0.f, q_ = 0.f;
        #pragma unroll
        for (int sl = 0; sl < 32; ++sl) {
          unsigned long long v = AT_LD((const unsigned long long*)(st + (sl * 32 + m) * 2));
          s_ += __uint_as_float((unsigned)v);
          q_ += __uint_as_float((unsigned)(v >> 32));
        }
        float mu = s_ * (1.f / 512.f);
        float var = q_ * (1.f / 512.f) - mu * mu;
        mu1[m] = mu; rs1[m] = rsqrtf(var + 1e-3f);
      }
    }
    __syncthreads();
    // ---- MFMA: z-slice = A @ Wslice ----
    f32x4 acc[2][2] = {};
    {
      const short* asrc = (mm == 2) ? h1b : h0b;   // R1 reads h1[r-2], R0/W1' read h0[r-1]
      #pragma unroll
      for (int kb = 0; kb < 16; ++kb) {
        short8 a0 = *(const short8*)(asrc + ((kb * 2 + 0) * 64 + lane) * 8);
        short8 a1 = *(const short8*)(asrc + ((kb * 2 + 1) * 64 + lane) * 8);
        #pragma unroll
        for (int nf = 0; nf < 2; ++nf) {
          acc[0][nf] = __builtin_amdgcn_mfma_f32_16x16x32_bf16(a0, wr[kb][nf], acc[0][nf], 0, 0, 0);
          acc[1][nf] = __builtin_amdgcn_mfma_f32_16x16x32_bf16(a1, wr[kb][nf], acc[1][nf], 0, 0, 0);
        }
      }
    }
    __syncthreads();              // all waves done reading h0b before zbuf overwrites it
    {
      float* z = zbv + mm * 2112;
      #pragma unroll
      for (int mf = 0; mf < 2; ++mf)
        #pragma unroll
        for (int nf = 0; nf < 2; ++nf)
          #pragma unroll
          for (int q = 0; q < 4; ++q) {
            int row = mf * 16 + (lane >> 4) * 4 + q;
            int col = ch * 32 + nf * 16 + (lane & 15);
            z[row * 66 + col] = acc[mf][nf][q];
          }
    }
    __syncthreads();
    // ---- combine: gates, cell/phase updates (2 adjacent units/thread) ----
    const bool l0act = (r < T_STEPS);
    const bool l1act = (r >= 1 && r <= T_STEPS);
    for (int it = tid; it < 512; it += NTHR) {
      int layer = it >> 8;
      int id2 = it & 255;
      int m = id2 >> 3;
      int u0 = (id2 & 7) << 1;
      int uglob0 = slice * 16 + u0;
      if (layer == 0) {
        if (!l0act) continue;
        const float* xp = x + ((size_t)(gm0 + m) * T_STEPS + r) * 3;
        float x0 = xp[0], x1 = xp[1], x2 = xp[2];
        float tmv = times[(size_t)(gm0 + m) * T_STEPS + r];
        unsigned pack = 0;
        #pragma unroll
        for (int uu = 0; uu < 2; ++uu) {
          int u = u0 + uu, uglob = uglob0 + uu, id = m * 16 + u;
          float zg4[4];
          #pragma unroll
          for (int q = 0; q < 4; ++q) {
            int gcol = q * 512 + uglob;
            zg4[q] = zbv[m * 66 + q * 16 + u] + b0[gcol]
                   + x0 * W0[gcol] + x1 * W0[2048 + gcol] + x2 * W0[4096 + gcol];
          }
          float iv = sigm(zg4[0]), fv = sigm(zg4[1]), gv = tanh_f(zg4[2]), ov = sigm(zg4[3]);
          float cold = c0f[id], hold = h0f[id];
          float cp = fv * cold + iv * gv;
          float hp = ov * tanh_f(cp);
          float k = timegate(tmv, tau0[uglob], s0[uglob]);
          float hn = k * hp + (1.f - k) * hold;
          float cn = k * cp + (1.f - k) * cold;
          h0f[id] = hn; c0f[id] = cn;
          pack |= ((unsigned)(unsigned short)f2bf(hn)) << (16 * uu);
        }
        AT_ST((unsigned*)(H0b + ((size_t)bufB * 8 + g) * 16384 + fragidx(m, uglob0)), pack);
      } else {
        if (!l1act) continue;
        float mu0m = mu0[m], rs0m = rs0[m];
        float tmv = times[(size_t)(gm0 + m) * T_STEPS + (r - 1)];
        unsigned pack = 0;
        #pragma unroll
        for (int uu = 0; uu < 2; ++uu) {
          int u = u0 + uu, uglob = uglob0 + uu, id = m * 16 + u;
          float zg4[4];
          #pragma unroll
          for (int q = 0; q < 4; ++q) {
            int c = q * 16 + u;
            int gcol = q * 512 + uglob;
            float zA = zbv[2112 + m * 66 + c];   // h0 @ (g0.W1)
            float zB = zbv[4224 + m * 66 + c];   // h1 @ R1
            zg4[q] = rs0m * zA + zB + b1[gcol] + u1v[gcol] - mu0m * rs0m * v1v[gcol];
          }
          float iv = sigm(zg4[0]), fv = sigm(zg4[1]), gv = tanh_f(zg4[2]), ov = sigm(zg4[3]);
          float cold = c1f[id], hold = h1f[id];
          float cp = fv * cold + iv * gv;
          float hp = ov * tanh_f(cp);
          float k = timegate(tmv, tau1[uglob], s1[uglob]);
          float hn = k * hp + (1.f - k) * hold;
          float cn = k * cp + (1.f - k) * cold;
          h1f[id] = hn; c1f[id] = cn;
          pack |= ((unsigned)(unsigned short)f2bf(hn)) << (16 * uu);
        }
        AT_ST((unsigned*)(H1b + ((size_t)bufA * 8 + g) * 16384 + fragidx(m, uglob0)), pack);
      }
    }
    __syncthreads();
    // ---- partial LN stats + classifier head ----
    if (tid < 32) {
      if (l0act) {
        float s_ = 0.f, q_ = 0.f;
        #pragma unroll
        for (int u = 0; u < 16; ++u) { float v = h0f[tid * 16 + u]; s_ += v; q_ += v * v; }
        float* st = St0 + ((size_t)bufB * 8 + g) * 2048 + (slice * 32 + tid) * 2;
        unsigned long long pv = ((unsigned long long)__float_as_uint(q_) << 32) | __float_as_uint(s_);
        AT_ST((unsigned long long*)st, pv);
      }
    } else if (tid < 64) {
      if (l1act) {
        int m = tid - 32;
        float s_ = 0.f, q_ = 0.f;
        #pragma unroll
        for (int u = 0; u < 16; ++u) { float v = h1f[m * 16 + u]; s_ += v; q_ += v * v; }
        float* st = St1 + ((size_t)bufA * 8 + g) * 2048 + (slice * 32 + m) * 2;
        unsigned long long pv = ((unsigned long long)__float_as_uint(q_) << 32) | __float_as_uint(s_);
        AT_ST((unsigned long long*)st, pv);
      }
    } else if (wid == 1) {
      if (r >= 2) {  // head for step r-2, sample (g, slice); h1b holds version r-2
        int msam = slice;
        float lg[10];
        #pragma unroll
        for (int c = 0; c < 10; ++c) lg[c] = 0.f;
        for (int kk = 0; kk < 8; ++kk) {
          int k = lane * 8 + kk;
          float hv = bf2f(h1b[fragidx(msam, k)]);
          const float* wf = Wfp + k * 10;
          #pragma unroll
          for (int c = 0; c < 10; ++c) lg[c] += hv * wf[c];
        }
        #pragma unroll
        for (int off = 32; off > 0; off >>= 1)
          #pragma unroll
          for (int c = 0; c < 10; ++c) lg[c] += __shfl_down(lg[c], off, 64);
        if (lane == 0) {
          float m1 = mu1[msam], r1 = rs1[msam];
          float logit[10], mx = -1e30f;
          #pragma unroll
          for (int c = 0; c < 10; ++c) {
            logit[c] = r1 * lg[c] + ufv[c] - m1 * r1 * ufv[16 + c];
            mx = fmaxf(mx, logit[c]);
          }
          float ssum = 0.f;
          #pragma unroll
          for (int c = 0; c < 10; ++c) { logit[c] = expf(logit[c] - mx); ssum += logit[c]; }
          float inv = 1.f / ssum;
          float* op = out + ((size_t)(gm0 + msam) * T_STEPS + (r - 2)) * 10;
          #pragma unroll
          for (int c = 0; c < 10; ++c) op[c] = logit[c] * inv;
        }
      }
    }
    __syncthreads();   // compiler drains vmcnt(0) here: all sc1 stores acked at LLC
    // ---- intra-group barrier: relaxed atomics only, NO fences ----
    if (r < T_STEPS + 1) {
      if (tid == 0) {
        __hip_atomic_fetch_add(&cnt[g * 64], 1u, __ATOMIC_RELAXED, __HIP_MEMORY_SCOPE_AGENT);
        unsigned tgt = 32u * (unsigned)(r + 1);
        while (__hip_atomic_load(&cnt[g * 64], __ATOMIC_RELAXED, __HIP_MEMORY_SCOPE_AGENT) < tgt)
          __builtin_amdgcn_s_sleep(1);
      }
      __syncthreads();
    }
  }
}

extern "C" void kernel_launch(void* const* d_in, const int* in_sizes, int n_in,
                              void* d_out, int out_size, void* d_ws, size_t ws_size,
                              hipStream_t stream) {
  const float* x    = (const float*)d_in[0];
  const float* tms  = (const float*)d_in[1];
  const float* W0   = (const float*)d_in[2];
  const float* R0   = (const float*)d_in[3];
  const float* b0   = (const float*)d_in[4];
  const float* tau0 = (const float*)d_in[5];
  const float* s0   = (const float*)d_in[6];
  const float* g0   = (const float*)d_in[7];
  const float* be0  = (const float*)d_in[8];
  const float* W1   = (const float*)d_in[9];
  const float* R1   = (const float*)d_in[10];
  const float* b1   = (const float*)d_in[11];
  const float* tau1 = (const float*)d_in[12];
  const float* s1   = (const float*)d_in[13];
  const float* g1   = (const float*)d_in[14];
  const float* be1  = (const float*)d_in[15];
  const float* Wf   = (const float*)d_in[16];
  const float* bfv  = (const float*)d_in[17];

  char* ws = (char*)d_ws;
  short* Wswz = (short*)(ws + OFF_WSWZ);
  float* u1   = (float*)(ws + OFF_U1);
  float* v1   = (float*)(ws + OFF_V1);
  float* Wfp  = (float*)(ws + OFF_WFP);
  float* ufv  = (float*)(ws + OFF_UFV);
  short* H0b  = (short*)(ws + OFF_H0B);
  short* H1b  = (short*)(ws + OFF_H1B);
  float* St0  = (float*)(ws + OFF_ST0);
  float* St1  = (float*)(ws + OFF_ST1);
  unsigned* cnt = (unsigned*)(ws + OFF_CNT);

  hipFuncSetAttribute(reinterpret_cast<const void*>(plstm_persist),
                      hipFuncAttributeMaxDynamicSharedMemorySize, SMEM_BYTES);

  prep_weights<<<1536, 256, 0, stream>>>(R0, W1, R1, g0, Wswz);
  prep_vecs<<<8, 256, 0, stream>>>(W1, g0, be0, u1, v1);
  prep_head<<<20, 256, 0, stream>>>(Wf, g1, be1, bfv, Wfp, ufv);
  hipMemsetAsync(ws + OFF_H0B, 0, ZERO_BYTES, stream);
  plstm_persist<<<NB, NTHR, SMEM_BYTES, stream>>>(
      x, tms, W0, b0, tau0, s0, b1, tau1, s1,
      Wswz, u1, v1, Wfp, ufv, H0b, H1b, St0, St1, cnt, (float*)d_out);
}